// Round 5
// baseline (1116.917 us; speedup 1.0000x reference)
//
#include <hip/hip_runtime.h>
#include <stdint.h>

#define B_ 1024
#define N_ 224
#define NN_ (N_ * N_)

typedef unsigned short u16;
typedef unsigned int u32;
typedef __attribute__((ext_vector_type(8))) short s8v;  // bf16x8 MFMA frag (4 VGPR)
typedef __attribute__((ext_vector_type(4))) float f4v;  // fp32x4 acc

// fp32 -> bf16 round-to-nearest-even
__device__ __forceinline__ u16 f2bf(float f) {
  u32 u = __float_as_uint(f);
  u = (u + 0x7FFFu + ((u >> 16) & 1u)) >> 16;
  return (u16)u;
}
__device__ __forceinline__ float bf2f(u16 h) { return __uint_as_float((u32)h << 16); }
__device__ __forceinline__ float rec(u16 h, u16 l) { return bf2f(h) + bf2f(l); }

__device__ __forceinline__ void gload16(const void* g, void* l) {
  __builtin_amdgcn_global_load_lds(
      (const __attribute__((address_space(1))) uint32_t*)g,
      (__attribute__((address_space(3))) uint32_t*)l, 16, 0, 0);
}

// Split x (fp32) into hi/lo bf16 pairs, row-major AND transposed copies.
// Grid: 49 tiles (32x32) per matrix. Thread: (r = t>>3, c4 = (t&7)*4).
__global__ __launch_bounds__(256) void splitT(const float* __restrict__ x,
                                              u16* __restrict__ xh, u16* __restrict__ xl,
                                              u16* __restrict__ xhT, u16* __restrict__ xlT) {
  __shared__ u16 th[32][34];  // pad 34: transpose-read bank spread
  __shared__ u16 tl[32][34];
  const int bid = blockIdx.x;
  const int mat = bid / 49, t2 = bid % 49;
  const int tm = (t2 / 7) * 32, tn = (t2 % 7) * 32;
  const int t = threadIdx.x;
  const int r = t >> 3, c4 = (t & 7) << 2;
  const size_t o = (size_t)mat * NN_ + (size_t)(tm + r) * N_ + tn + c4;
  const float4 v = *(const float4*)(x + o);
  u16 h0 = f2bf(v.x), h1 = f2bf(v.y), h2 = f2bf(v.z), h3 = f2bf(v.w);
  u16 l0 = f2bf(v.x - bf2f(h0)), l1 = f2bf(v.y - bf2f(h1));
  u16 l2 = f2bf(v.z - bf2f(h2)), l3 = f2bf(v.w - bf2f(h3));
  ushort4 hv = {h0, h1, h2, h3}, lv = {l0, l1, l2, l3};
  *(ushort4*)(xh + o) = hv;
  *(ushort4*)(xl + o) = lv;
  th[r][c4] = h0; th[r][c4 + 1] = h1; th[r][c4 + 2] = h2; th[r][c4 + 3] = h3;
  tl[r][c4] = l0; tl[r][c4 + 1] = l1; tl[r][c4 + 2] = l2; tl[r][c4 + 3] = l3;
  __syncthreads();
  // xT[tn+r][tm+c4+i] = x[tm+c4+i][tn+r]
  ushort4 thv = {th[c4][r], th[c4 + 1][r], th[c4 + 2][r], th[c4 + 3][r]};
  ushort4 tlv = {tl[c4][r], tl[c4 + 1][r], tl[c4 + 2][r], tl[c4 + 3][r]};
  const size_t oT = (size_t)mat * NN_ + (size_t)(tn + r) * N_ + tm + c4;
  *(ushort4*)(xhT + oT) = thv;
  *(ushort4*)(xlT + oT) = tlv;
}

// NT split-bf16 MFMA gemm: C[m][n] = sum_k A[m][k]*BT[n][k], A=(Ah+Al), B=(BTh+BTl),
// C = Ah.Bh + Ah.Bl + Al.Bh accumulated fp32, written back as bf16 pair.
// Per batch matrix: 4 overlapping 128x128 tiles at m0,n0 in {0,96} (K=224 exact).
// LDS row = 128B: 8 chunks of 16B = {h k-chunks 0-3, l k-chunks 0-3}, chunk XOR-swizzled
// by (row&7) -> ds_read_b128 frag reads are 2-way max (free, m136). Staged via
// global_load_lds (linear lane->slot) with pre-swizzled per-lane global source (rule 21).
__global__ __launch_bounds__(256, 2) void gemmNT(const u16* __restrict__ Ah, const u16* __restrict__ Al,
                                                 const u16* __restrict__ BTh, const u16* __restrict__ BTl,
                                                 u16* __restrict__ Ch, u16* __restrict__ Cl) {
  __shared__ __align__(16) u16 As[2][128][64];
  __shared__ __align__(16) u16 Bs[2][128][64];

  // bijective XCD swizzle (m204): each XCD gets a contiguous run of wg ids
  const int nwg = gridDim.x, bid = blockIdx.x;
  const int q = nwg >> 3, rr = nwg & 7, xcd = bid & 7, pos = bid >> 3;
  const int wg = (xcd < rr) ? (xcd * (q + 1) + pos) : (rr * (q + 1) + (xcd - rr) * q + pos);
  const int mat = wg >> 2, t2 = wg & 3;
  const int m0 = (t2 & 1) * 96, n0 = (t2 >> 1) * 96;
  const size_t mo = (size_t)mat * NN_;
  const u16* A0 = Ah + mo;
  const u16* A1 = Al + mo;
  const u16* B0 = BTh + mo;
  const u16* B1 = BTl + mo;

  const int t = threadIdx.x;
  const int l = t & 63, w = t >> 6;
  const int wm = w & 1, wn = w >> 1;  // wave -> 64x64 quadrant
  const int lg = l >> 4, l15 = l & 15;

  f4v acc[4][4];
#pragma unroll
  for (int i = 0; i < 4; ++i)
#pragma unroll
    for (int j = 0; j < 4; ++j) acc[i][j] = (f4v){0.f, 0.f, 0.f, 0.f};

  auto stage = [&](int buf, int k0) {
#pragma unroll
    for (int i = 0; i < 4; ++i) {
      const int s = i * 256 + t;          // LDS 16B-slot, linear in lane within wave
      const int row = s >> 3, p = s & 7;  // physical chunk p
      const int c = p ^ (row & 7);        // logical chunk: 0-3 = h k-chunk c, 4-7 = l k-chunk c-4
      const int g = c & 3;
      const u16* ga = (c < 4) ? A0 : A1;
      const u16* gb = (c < 4) ? B0 : B1;
      gload16(ga + (size_t)(m0 + row) * N_ + k0 + g * 8, &As[buf][row][p * 8]);
      gload16(gb + (size_t)(n0 + row) * N_ + k0 + g * 8, &Bs[buf][row][p * 8]);
    }
  };

  stage(0, 0);
  int cur = 0;
  for (int kt = 0; kt < 7; ++kt) {  // K = 7 * 32
    __syncthreads();                // drains vmcnt -> buf[cur] ready; buf[cur^1] free
    if (kt < 6) stage(cur ^ 1, (kt + 1) * 32);
    const u16(*Ab)[64] = As[cur];
    const u16(*Bb)[64] = Bs[cur];
    s8v ah[4], al[4], bh[4], bl[4];
#pragma unroll
    for (int i = 0; i < 4; ++i) {
      const int ra = wm * 64 + i * 16 + l15;
      const int rb = wn * 64 + i * 16 + l15;
      ah[i] = *(const s8v*)&Ab[ra][(lg ^ (ra & 7)) * 8];
      al[i] = *(const s8v*)&Ab[ra][((4 + lg) ^ (ra & 7)) * 8];
      bh[i] = *(const s8v*)&Bb[rb][(lg ^ (rb & 7)) * 8];
      bl[i] = *(const s8v*)&Bb[rb][((4 + lg) ^ (rb & 7)) * 8];
    }
#pragma unroll
    for (int i = 0; i < 4; ++i)
#pragma unroll
      for (int j = 0; j < 4; ++j) {
        acc[i][j] = __builtin_amdgcn_mfma_f32_16x16x32_bf16(ah[i], bh[j], acc[i][j], 0, 0, 0);
        acc[i][j] = __builtin_amdgcn_mfma_f32_16x16x32_bf16(ah[i], bl[j], acc[i][j], 0, 0, 0);
        acc[i][j] = __builtin_amdgcn_mfma_f32_16x16x32_bf16(al[i], bh[j], acc[i][j], 0, 0, 0);
      }
    cur ^= 1;
  }

  // Epilogue: C/D layout col = lane&15, row = (lane>>4)*4 + reg (m89-verified).
  u16* cph = Ch + mo;
  u16* cpl = Cl + mo;
#pragma unroll
  for (int i = 0; i < 4; ++i)
#pragma unroll
    for (int j = 0; j < 4; ++j)
#pragma unroll
      for (int qd = 0; qd < 4; ++qd) {
        const float v = acc[i][j][qd];
        const int row = m0 + wm * 64 + i * 16 + lg * 4 + qd;
        const int col = n0 + wn * 64 + j * 16 + l15;
        const u16 hh = f2bf(v);
        const u16 ll = f2bf(v - bf2f(hh));
        cph[(size_t)row * N_ + col] = hh;
        cpl[(size_t)row * N_ + col] = ll;
      }
}

// d2=diag(P2), d3=diag(P3), d4[n]=sum_k P2[n,k]P2[k,n], d5[n]=sum_k P3[n,k]P2[k,n].
// P2,P3 given as bf16 pairs (h+l reconstructs to ~2^-17 rel).
__global__ __launch_bounds__(256) void diagk(const u16* __restrict__ P2h, const u16* __restrict__ P2l,
                                             const u16* __restrict__ P3h, const u16* __restrict__ P3l,
                                             float* __restrict__ dg, int bBase) {
  __shared__ float s2[N_][17];
  __shared__ float s3[N_][17];
  const int b = blockIdx.x;
  const size_t mo = (size_t)b * NN_;
  const u16 *p2h = P2h + mo, *p2l = P2l + mo, *p3h = P3h + mo, *p3l = P3l + mo;
  const int gb = bBase + b;
  const int t = threadIdx.x;
  float d4 = 0.f, d5 = 0.f;
  for (int kb = 0; kb < N_; kb += 16) {
    __syncthreads();
#pragma unroll
    for (int base = 0; base < N_ * 16; base += 256) {  // 3584 = 14*256
      const int f = base + t;
      const int n = f >> 4, j = f & 15;
      const size_t idx = (size_t)n * N_ + kb + j;
      s2[n][j] = rec(p2h[idx], p2l[idx]);
      s3[n][j] = rec(p3h[idx], p3l[idx]);
    }
    __syncthreads();
    if (t < N_) {
#pragma unroll
      for (int j = 0; j < 16; ++j) {
        const size_t ci = (size_t)(kb + j) * N_ + t;  // column, coalesced
        const float c2 = rec(p2h[ci], p2l[ci]);
        d4 = fmaf(s2[t][j], c2, d4);
        d5 = fmaf(s3[t][j], c2, d5);
      }
    }
  }
  if (t < N_) {
    const size_t di = (size_t)t * N_ + t;
    dg[((size_t)0 * B_ + gb) * N_ + t] = rec(p2h[di], p2l[di]);
    dg[((size_t)1 * B_ + gb) * N_ + t] = rec(p3h[di], p3l[di]);
    dg[((size_t)2 * B_ + gb) * N_ + t] = d4;
    dg[((size_t)3 * B_ + gb) * N_ + t] = d5;
  }
}

// One wave per batch: T[i][j] = sum_n d_i[n]^(j+1); out = sum coef*T/(N*N)^(i+j+2).
__global__ __launch_bounds__(256) void combine(const float* __restrict__ dg,
                                               const float* __restrict__ coef,
                                               float* __restrict__ out) {
  const int lane = threadIdx.x & 63;
  const int b = blockIdx.x * 4 + (threadIdx.x >> 6);
  float T[4][4] = {};
  for (int n = lane; n < N_; n += 64) {
#pragma unroll
    for (int i = 0; i < 4; ++i) {
      const float d = dg[((size_t)i * B_ + b) * N_ + n];
      float p = d;
#pragma unroll
      for (int j = 0; j < 4; ++j) {
        T[i][j] += p;
        p *= d;
      }
    }
  }
#pragma unroll
  for (int i = 0; i < 4; ++i)
#pragma unroll
    for (int j = 0; j < 4; ++j)
#pragma unroll
      for (int s = 32; s > 0; s >>= 1) T[i][j] += __shfl_xor(T[i][j], s, 64);
  if (lane == 0) {
    double acc = 0.0;
#pragma unroll
    for (int i = 0; i < 4; ++i)
#pragma unroll
      for (int j = 0; j < 4; ++j) {
        double norm = 1.0;
        for (int e = 0; e < i + j + 2; ++e) norm *= (double)(N_ * N_);
        acc += (double)coef[i * 4 + j] * ((double)T[i][j] / norm);
      }
    out[b] = (float)acc;
  }
}

extern "C" void kernel_launch(void* const* d_in, const int* in_sizes, int n_in,
                              void* d_out, int out_size, void* d_ws, size_t ws_size,
                              hipStream_t stream) {
  (void)in_sizes; (void)n_in; (void)out_size;
  const float* x = (const float*)d_in[0];
  const float* coef = (const float*)d_in[1];
  float* out = (float*)d_out;
  char* ws = (char*)d_ws;

  size_t off = 0;
  auto alloc = [&](size_t bytes) -> void* {
    off = (off + 255) & ~(size_t)255;
    void* p = ws + off;
    off += bytes;
    return p;
  };

  float* dg = (float*)alloc((size_t)4 * B_ * N_ * sizeof(float));

  // 8 bf16 arrays per matrix: xh,xl,xhT,xlT,P2h,P2l,P3h,P3l -> 802816 B/matrix
  const size_t perMat = (size_t)8 * NN_ * sizeof(u16);
  size_t avail = (ws_size > off + 256) ? (ws_size - off - 256) : 0;
  long long Cc = (long long)(avail / perMat);
  if (Cc < 1) Cc = 1;
  if (Cc > B_) Cc = B_;
  const int C = (int)Cc;
  const size_t matEls = (size_t)C * NN_;
  u16* xh = (u16*)alloc(matEls * 2);
  u16* xl = (u16*)alloc(matEls * 2);
  u16* xhT = (u16*)alloc(matEls * 2);
  u16* xlT = (u16*)alloc(matEls * 2);
  u16* P2h = (u16*)alloc(matEls * 2);
  u16* P2l = (u16*)alloc(matEls * 2);
  u16* P3h = (u16*)alloc(matEls * 2);
  u16* P3l = (u16*)alloc(matEls * 2);

  for (int b0 = 0; b0 < B_; b0 += C) {
    const int cb = (B_ - b0 < C) ? (B_ - b0) : C;
    splitT<<<49 * cb, 256, 0, stream>>>(x + (size_t)b0 * NN_, xh, xl, xhT, xlT);
    gemmNT<<<4 * cb, 256, 0, stream>>>(xh, xl, xhT, xlT, P2h, P2l);    // P2 = x^2
    gemmNT<<<4 * cb, 256, 0, stream>>>(P2h, P2l, xhT, xlT, P3h, P3l);  // P3 = P2*x
    diagk<<<cb, 256, 0, stream>>>(P2h, P2l, P3h, P3l, dg, b0);
  }
  combine<<<256, 256, 0, stream>>>(dg, coef, out);
}

// Round 9
// 1009.789 us; speedup vs baseline: 1.1061x; 1.1061x over previous
//
#include <hip/hip_runtime.h>
#include <stdint.h>

#define B_ 1024
#define N_ 224
#define NN_ (N_ * N_)

typedef unsigned short u16;
typedef unsigned int u32;
typedef __attribute__((ext_vector_type(8))) short s8v;           // bf16x8 MFMA frag (4 VGPR)
typedef __attribute__((ext_vector_type(4))) float f4v;           // fp32x4 acc
typedef __attribute__((ext_vector_type(8))) unsigned short us8;  // u16x8 (16B load)

// fp32 -> bf16 round-to-nearest-even
__device__ __forceinline__ u16 f2bf(float f) {
  u32 u = __float_as_uint(f);
  u = (u + 0x7FFFu + ((u >> 16) & 1u)) >> 16;
  return (u16)u;
}
__device__ __forceinline__ float bf2f(u16 h) { return __uint_as_float((u32)h << 16); }
__device__ __forceinline__ float rec(u16 h, u16 l) { return bf2f(h) + bf2f(l); }

__device__ __forceinline__ void gload16(const void* g, void* l) {
  __builtin_amdgcn_global_load_lds(
      (const __attribute__((address_space(1))) uint32_t*)g,
      (__attribute__((address_space(3))) uint32_t*)l, 16, 0, 0);
}

// Split x (fp32) into hi/lo bf16 pairs, row-major AND transposed copies.
// Grid: 49 tiles (32x32) per matrix. Thread: (r = t>>3, c4 = (t&7)*4).
__global__ __launch_bounds__(256) void splitT(const float* __restrict__ x,
                                              u16* __restrict__ xh, u16* __restrict__ xl,
                                              u16* __restrict__ xhT, u16* __restrict__ xlT) {
  __shared__ u16 th[32][34];  // pad 34: transpose-read bank spread
  __shared__ u16 tl[32][34];
  const int bid = blockIdx.x;
  const int mat = bid / 49, t2 = bid % 49;
  const int tm = (t2 / 7) * 32, tn = (t2 % 7) * 32;
  const int t = threadIdx.x;
  const int r = t >> 3, c4 = (t & 7) << 2;
  const size_t o = (size_t)mat * NN_ + (size_t)(tm + r) * N_ + tn + c4;
  const float4 v = *(const float4*)(x + o);
  u16 h0 = f2bf(v.x), h1 = f2bf(v.y), h2 = f2bf(v.z), h3 = f2bf(v.w);
  u16 l0 = f2bf(v.x - bf2f(h0)), l1 = f2bf(v.y - bf2f(h1));
  u16 l2 = f2bf(v.z - bf2f(h2)), l3 = f2bf(v.w - bf2f(h3));
  ushort4 hv = {h0, h1, h2, h3}, lv = {l0, l1, l2, l3};
  *(ushort4*)(xh + o) = hv;
  *(ushort4*)(xl + o) = lv;
  th[r][c4] = h0; th[r][c4 + 1] = h1; th[r][c4 + 2] = h2; th[r][c4 + 3] = h3;
  tl[r][c4] = l0; tl[r][c4 + 1] = l1; tl[r][c4 + 2] = l2; tl[r][c4 + 3] = l3;
  __syncthreads();
  // xT[tn+r][tm+c4+i] = x[tm+c4+i][tn+r]
  ushort4 thv = {th[c4][r], th[c4 + 1][r], th[c4 + 2][r], th[c4 + 3][r]};
  ushort4 tlv = {tl[c4][r], tl[c4 + 1][r], tl[c4 + 2][r], tl[c4 + 3][r]};
  const size_t oT = (size_t)mat * NN_ + (size_t)(tn + r) * N_ + tm + c4;
  *(ushort4*)(xhT + oT) = thv;
  *(ushort4*)(xlT + oT) = tlv;
}

// NT split-bf16 MFMA gemm: C[m][n] = sum_k A[m][k]*BT[n][k], A=(Ah+Al), B=(BTh+BTl),
// C = Ah.Bh + Ah.Bl + Al.Bh accumulated fp32, written back as bf16 pair.
// Per batch matrix: 4 overlapping 128x128 tiles at m0,n0 in {0,96} (K=224 exact).
// If CTh != nullptr, also writes the transposed pair (for the P2 gemm: P2T feeds diagk).
__global__ __launch_bounds__(256, 2) void gemmNT(const u16* __restrict__ Ah, const u16* __restrict__ Al,
                                                 const u16* __restrict__ BTh, const u16* __restrict__ BTl,
                                                 u16* __restrict__ Ch, u16* __restrict__ Cl,
                                                 u16* __restrict__ CTh, u16* __restrict__ CTl) {
  __shared__ __align__(16) u16 As[2][128][64];
  __shared__ __align__(16) u16 Bs[2][128][64];

  // bijective XCD swizzle (m204): each XCD gets a contiguous run of wg ids
  const int nwg = gridDim.x, bid = blockIdx.x;
  const int q = nwg >> 3, rr = nwg & 7, xcd = bid & 7, pos = bid >> 3;
  const int wg = (xcd < rr) ? (xcd * (q + 1) + pos) : (rr * (q + 1) + (xcd - rr) * q + pos);
  const int mat = wg >> 2, t2 = wg & 3;
  const int m0 = (t2 & 1) * 96, n0 = (t2 >> 1) * 96;
  const size_t mo = (size_t)mat * NN_;
  const u16* A0 = Ah + mo;
  const u16* A1 = Al + mo;
  const u16* B0 = BTh + mo;
  const u16* B1 = BTl + mo;

  const int t = threadIdx.x;
  const int l = t & 63, w = t >> 6;
  const int wm = w & 1, wn = w >> 1;  // wave -> 64x64 quadrant
  const int lg = l >> 4, l15 = l & 15;

  f4v acc[4][4];
#pragma unroll
  for (int i = 0; i < 4; ++i)
#pragma unroll
    for (int j = 0; j < 4; ++j) acc[i][j] = (f4v){0.f, 0.f, 0.f, 0.f};

  auto stage = [&](int buf, int k0) {
#pragma unroll
    for (int i = 0; i < 4; ++i) {
      const int s = i * 256 + t;          // LDS 16B-slot, linear in lane within wave
      const int row = s >> 3, p = s & 7;  // physical chunk p
      const int c = p ^ (row & 7);        // logical chunk: 0-3 = h k-chunk c, 4-7 = l k-chunk c-4
      const int g = c & 3;
      const u16* ga = (c < 4) ? A0 : A1;
      const u16* gb = (c < 4) ? B0 : B1;
      gload16(ga + (size_t)(m0 + row) * N_ + k0 + g * 8, &As[buf][row][p * 8]);
      gload16(gb + (size_t)(n0 + row) * N_ + k0 + g * 8, &Bs[buf][row][p * 8]);
    }
  };

  stage(0, 0);
  int cur = 0;
  for (int kt = 0; kt < 7; ++kt) {  // K = 7 * 32
    __syncthreads();                // drains vmcnt -> buf[cur] ready; buf[cur^1] free
    if (kt < 6) stage(cur ^ 1, (kt + 1) * 32);
    const u16(*Ab)[64] = As[cur];
    const u16(*Bb)[64] = Bs[cur];
    s8v ah[4], al[4], bh[4], bl[4];
#pragma unroll
    for (int i = 0; i < 4; ++i) {
      const int ra = wm * 64 + i * 16 + l15;
      const int rb = wn * 64 + i * 16 + l15;
      ah[i] = *(const s8v*)&Ab[ra][(lg ^ (ra & 7)) * 8];
      al[i] = *(const s8v*)&Ab[ra][((4 + lg) ^ (ra & 7)) * 8];
      bh[i] = *(const s8v*)&Bb[rb][(lg ^ (rb & 7)) * 8];
      bl[i] = *(const s8v*)&Bb[rb][((4 + lg) ^ (rb & 7)) * 8];
    }
#pragma unroll
    for (int i = 0; i < 4; ++i)
#pragma unroll
      for (int j = 0; j < 4; ++j) {
        acc[i][j] = __builtin_amdgcn_mfma_f32_16x16x32_bf16(ah[i], bh[j], acc[i][j], 0, 0, 0);
        acc[i][j] = __builtin_amdgcn_mfma_f32_16x16x32_bf16(ah[i], bl[j], acc[i][j], 0, 0, 0);
        acc[i][j] = __builtin_amdgcn_mfma_f32_16x16x32_bf16(al[i], bh[j], acc[i][j], 0, 0, 0);
      }
    cur ^= 1;
  }

  // Epilogue: C/D layout col = lane&15, row = (lane>>4)*4 + reg (m89-verified).
  u16* cph = Ch + mo;
  u16* cpl = Cl + mo;
#pragma unroll
  for (int i = 0; i < 4; ++i)
#pragma unroll
    for (int j = 0; j < 4; ++j) {
      u16 hq[4], lq[4];
#pragma unroll
      for (int qd = 0; qd < 4; ++qd) {
        const float v = acc[i][j][qd];
        hq[qd] = f2bf(v);
        lq[qd] = f2bf(v - bf2f(hq[qd]));
        const int row = m0 + wm * 64 + i * 16 + lg * 4 + qd;
        const int col = n0 + wn * 64 + j * 16 + l15;
        cph[(size_t)row * N_ + col] = hq[qd];
        cpl[(size_t)row * N_ + col] = lq[qd];
      }
      if (CTh) {  // transposed pair: the 4 qd rows are consecutive along CT's row
        const int row0 = m0 + wm * 64 + i * 16 + lg * 4;
        const int col = n0 + wn * 64 + j * 16 + l15;
        const ushort4 hv = {hq[0], hq[1], hq[2], hq[3]};
        const ushort4 lv = {lq[0], lq[1], lq[2], lq[3]};
        *(ushort4*)(CTh + mo + (size_t)col * N_ + row0) = hv;
        *(ushort4*)(CTl + mo + (size_t)col * N_ + row0) = lv;
      }
    }
}

// Diagonals pass, zero LDS. Grid = 7 * nMats; block handles 32 rows of one matrix.
// Thread (r8 = t>>3, sub = t&7): row n = p*32 + r8; sub-lanes cover the 28 us8 chunks
// of the row (stride 8) -> per-inst 8 subs x 16B = 128B contiguous per row-group,
// fully coalesced. d4 = dot(P2row, P2Trow), d5 = dot(P3row, P2Trow); diag elements
// come free from the chunk already in registers. 3-step shfl_xor sub-reduction.
__global__ __launch_bounds__(256) void diagk(const u16* __restrict__ P2h, const u16* __restrict__ P2l,
                                             const u16* __restrict__ P2Th, const u16* __restrict__ P2Tl,
                                             const u16* __restrict__ P3h, const u16* __restrict__ P3l,
                                             float* __restrict__ dg, int bBase) {
  const int bid = blockIdx.x;
  const int b = bid / 7, p = bid % 7;
  const size_t mo = (size_t)b * NN_;
  const int gb = bBase + b;
  const int t = threadIdx.x;
  const int r8 = t >> 3, sub = t & 7;
  const int n = p * 32 + r8;
  const int gd = n >> 3;  // chunk containing the diagonal element

  float d4 = 0.f, d5 = 0.f, d2 = 0.f, d3 = 0.f;
  bool own = false;
  for (int g = sub; g < 28; g += 8) {
    const size_t gi = mo + (size_t)n * N_ + g * 8;
    const us8 a2h = *(const us8*)(P2h + gi), a2l = *(const us8*)(P2l + gi);
    const us8 tth = *(const us8*)(P2Th + gi), ttl = *(const us8*)(P2Tl + gi);
    const us8 a3h = *(const us8*)(P3h + gi), a3l = *(const us8*)(P3l + gi);
#pragma unroll
    for (int i = 0; i < 8; ++i) {
      const float tv = rec(tth[i], ttl[i]);
      d4 = fmaf(rec(a2h[i], a2l[i]), tv, d4);
      d5 = fmaf(rec(a3h[i], a3l[i]), tv, d5);
    }
    if (g == gd) {
      own = true;
      d2 = rec(a2h[n & 7], a2l[n & 7]);
      d3 = rec(a3h[n & 7], a3l[n & 7]);
    }
  }
#pragma unroll
  for (int m = 1; m < 8; m <<= 1) {
    d4 += __shfl_xor(d4, m, 64);
    d5 += __shfl_xor(d5, m, 64);
  }
  if (sub == 0) {
    dg[((size_t)2 * B_ + gb) * N_ + n] = d4;
    dg[((size_t)3 * B_ + gb) * N_ + n] = d5;
  }
  if (own) {
    dg[((size_t)0 * B_ + gb) * N_ + n] = d2;
    dg[((size_t)1 * B_ + gb) * N_ + n] = d3;
  }
}

// One wave per batch: T[i][j] = sum_n d_i[n]^(j+1); out = sum coef*T/(N*N)^(i+j+2).
__global__ __launch_bounds__(256) void combine(const float* __restrict__ dg,
                                               const float* __restrict__ coef,
                                               float* __restrict__ out) {
  const int lane = threadIdx.x & 63;
  const int b = blockIdx.x * 4 + (threadIdx.x >> 6);
  float T[4][4] = {};
  for (int n = lane; n < N_; n += 64) {
#pragma unroll
    for (int i = 0; i < 4; ++i) {
      const float d = dg[((size_t)i * B_ + b) * N_ + n];
      float p = d;
#pragma unroll
      for (int j = 0; j < 4; ++j) {
        T[i][j] += p;
        p *= d;
      }
    }
  }
#pragma unroll
  for (int i = 0; i < 4; ++i)
#pragma unroll
    for (int j = 0; j < 4; ++j)
#pragma unroll
      for (int s = 32; s > 0; s >>= 1) T[i][j] += __shfl_xor(T[i][j], s, 64);
  if (lane == 0) {
    double acc = 0.0;
#pragma unroll
    for (int i = 0; i < 4; ++i)
#pragma unroll
      for (int j = 0; j < 4; ++j) {
        double norm = 1.0;
        for (int e = 0; e < i + j + 2; ++e) norm *= (double)(N_ * N_);
        acc += (double)coef[i * 4 + j] * ((double)T[i][j] / norm);
      }
    out[b] = (float)acc;
  }
}

extern "C" void kernel_launch(void* const* d_in, const int* in_sizes, int n_in,
                              void* d_out, int out_size, void* d_ws, size_t ws_size,
                              hipStream_t stream) {
  (void)in_sizes; (void)n_in; (void)out_size;
  const float* x = (const float*)d_in[0];
  const float* coef = (const float*)d_in[1];
  float* out = (float*)d_out;
  char* ws = (char*)d_ws;

  size_t off = 0;
  auto alloc = [&](size_t bytes) -> void* {
    off = (off + 255) & ~(size_t)255;
    void* p = ws + off;
    off += bytes;
    return p;
  };

  float* dg = (float*)alloc((size_t)4 * B_ * N_ * sizeof(float));

  // 10 bf16 arrays per matrix: xh,xl,xhT,xlT,P2h,P2l,P2Th,P2Tl,P3h,P3l -> ~1MB/matrix
  const size_t perMat = (size_t)10 * NN_ * sizeof(u16);
  size_t avail = (ws_size > off + 256) ? (ws_size - off - 256) : 0;
  long long Cc = (long long)(avail / perMat);
  if (Cc < 1) Cc = 1;
  if (Cc > B_) Cc = B_;
  const int C = (int)Cc;
  const size_t matEls = (size_t)C * NN_;
  u16* xh = (u16*)alloc(matEls * 2);
  u16* xl = (u16*)alloc(matEls * 2);
  u16* xhT = (u16*)alloc(matEls * 2);
  u16* xlT = (u16*)alloc(matEls * 2);
  u16* P2h = (u16*)alloc(matEls * 2);
  u16* P2l = (u16*)alloc(matEls * 2);
  u16* P2Th = (u16*)alloc(matEls * 2);
  u16* P2Tl = (u16*)alloc(matEls * 2);
  u16* P3h = (u16*)alloc(matEls * 2);
  u16* P3l = (u16*)alloc(matEls * 2);

  for (int b0 = 0; b0 < B_; b0 += C) {
    const int cb = (B_ - b0 < C) ? (B_ - b0) : C;
    splitT<<<49 * cb, 256, 0, stream>>>(x + (size_t)b0 * NN_, xh, xl, xhT, xlT);
    gemmNT<<<4 * cb, 256, 0, stream>>>(xh, xl, xhT, xlT, P2h, P2l, P2Th, P2Tl);        // P2 = x^2 (+P2T)
    gemmNT<<<4 * cb, 256, 0, stream>>>(P2h, P2l, xhT, xlT, P3h, P3l, nullptr, nullptr); // P3 = P2*x
    diagk<<<7 * cb, 256, 0, stream>>>(P2h, P2l, P2Th, P2Tl, P3h, P3l, dg, b0);
  }
  combine<<<256, 256, 0, stream>>>(dg, coef, out);
}